// Round 1
// baseline (12829.131 us; speedup 1.0000x reference)
//
#include <hip/hip_runtime.h>

// Problem: T=128, B=256, D_G=512, D_H=1024
//   zg = z @ W_g^T + b_h   (one big GEMM, precomputed)
//   h_t = relu(LN(h_{t-1} @ W_h^T + zg_t)), h_0 = 0; out = all h_t (fp32)
//
// Strategy: persistent RNN kernel, 256 blocks x 256 threads (1 block/CU).
//   16 row-groups (16 batch rows each) x 16 column-members (64 cols each).
//   W_h slice lives in 128 VGPRs per lane (pre-swizzled to MFMA B-operand
//   layout). Group-local device-scope barriers (not grid-wide).

#define T_STEPS 128
#define B_SZ    256
#define DG      512
#define DH      1024

typedef short s16x8 __attribute__((ext_vector_type(8)));   // 8 bf16 (4 VGPRs)
typedef float f32x4 __attribute__((ext_vector_type(4)));

__device__ inline short f2bf(float f) {
  unsigned u = __builtin_bit_cast(unsigned, f);
  unsigned r = (u + 0x7fffu + ((u >> 16) & 1u)) >> 16;   // RNE
  return (short)r;
}
__device__ inline float bf2f(short h) {
  unsigned u = ((unsigned)(unsigned short)h) << 16;
  return __builtin_bit_cast(float, u);
}
__device__ inline s16x8 pk8(f32x4 a, f32x4 b) {
  s16x8 r;
  r[0] = f2bf(a[0]); r[1] = f2bf(a[1]); r[2] = f2bf(a[2]); r[3] = f2bf(a[3]);
  r[4] = f2bf(b[0]); r[5] = f2bf(b[1]); r[6] = f2bf(b[2]); r[7] = f2bf(b[3]);
  return r;
}
__device__ inline f32x4 mfma16x32(s16x8 a, s16x8 b, f32x4 c) {
  return __builtin_amdgcn_mfma_f32_16x16x32_bf16(a, b, c, 0, 0, 0);
}
// sum across the 16 lanes of a quad-row group (lane^{1,2,4,8})
__device__ inline float rsum16(float v) {
  v += __shfl_xor(v, 1);
  v += __shfl_xor(v, 2);
  v += __shfl_xor(v, 4);
  v += __shfl_xor(v, 8);
  return v;
}

// ---------------------------------------------------------------------------
// prep: build W_h fragments in MFMA B-operand lane layout (bf16), zero h and
// barriers. frag layout: [memblk 16][wave 4][kstep 32][lane 64][j 8]
//   value = W_h[memblk*64 + wave*16 + (lane&15)][kstep*32 + (lane>>4)*8 + j]
// ---------------------------------------------------------------------------
__global__ __launch_bounds__(256) void prep_kernel(
    const float* __restrict__ Wh, short* __restrict__ frag_w,
    unsigned* __restrict__ h_zero, int* __restrict__ bars) {
  int i = blockIdx.x * 256 + threadIdx.x;              // grid = 4096 -> 1,048,576
  int j    = i & 7;
  int lane = (i >> 3) & 63;
  int ks   = (i >> 9) & 31;
  int w    = (i >> 14) & 3;
  int b    = i >> 16;
  int row = b * 64 + w * 16 + (lane & 15);
  int col = ks * 32 + (lane >> 4) * 8 + j;
  frag_w[i] = f2bf(Wh[row * DH + col]);
  if (i < (B_SZ * DH / 2)) h_zero[i] = 0u;             // h_buf: 256*1024 bf16
  if (i < 512) bars[i] = 0;
}

// ---------------------------------------------------------------------------
// zg GEMM: zg[t*B+b][n] = sum_k z[t*B+b][k]*W_g[n][k] + b_h[n]  (bf16 out)
// M=32768, N=1024, K=512. 128x128 tile, 256 thr, 4 waves in 2x2, BK=32.
// LDS rows padded to 40 shorts (80 B = 5*16 -> aligned b128, 2-way banks).
// ---------------------------------------------------------------------------
__global__ __launch_bounds__(256) void zg_gemm(
    const float* __restrict__ Z, const float* __restrict__ Wg,
    const float* __restrict__ bh, short* __restrict__ zg) {
  const int tid  = threadIdx.x;
  const int m0   = blockIdx.x * 128;
  const int n0   = blockIdx.y * 128;
  const int w    = tid >> 6, lane = tid & 63, ln = lane & 15, quad = lane >> 4;
  const int wm   = w & 1, wn = w >> 1;
  const int srow = tid >> 1, shalf = tid & 1;          // staging: 16 floats each

  __shared__ short As[128 * 40];
  __shared__ short Bs[128 * 40];
  f32x4 acc[4][4] = {};

  for (int k0 = 0; k0 < DG; k0 += 32) {
    __syncthreads();
    {
      const float* sA = Z + (m0 + srow) * DG + k0 + shalf * 16;
      f32x4 a0 = *(const f32x4*)sA,     a1 = *(const f32x4*)(sA + 4);
      f32x4 a2 = *(const f32x4*)(sA + 8), a3 = *(const f32x4*)(sA + 12);
      s16x8* dA = (s16x8*)&As[srow * 40 + shalf * 16];
      dA[0] = pk8(a0, a1); dA[1] = pk8(a2, a3);
      const float* sB = Wg + (n0 + srow) * DG + k0 + shalf * 16;
      f32x4 b0 = *(const f32x4*)sB,     b1 = *(const f32x4*)(sB + 4);
      f32x4 b2 = *(const f32x4*)(sB + 8), b3 = *(const f32x4*)(sB + 12);
      s16x8* dB = (s16x8*)&Bs[srow * 40 + shalf * 16];
      dB[0] = pk8(b0, b1); dB[1] = pk8(b2, b3);
    }
    __syncthreads();
    s16x8 af[4], bf[4];
#pragma unroll
    for (int i = 0; i < 4; i++) {
      af[i] = *(const s16x8*)&As[(wm * 64 + i * 16 + ln) * 40 + quad * 8];
      bf[i] = *(const s16x8*)&Bs[(wn * 64 + i * 16 + ln) * 40 + quad * 8];
    }
#pragma unroll
    for (int mi = 0; mi < 4; mi++)
#pragma unroll
      for (int ni = 0; ni < 4; ni++)
        acc[mi][ni] = mfma16x32(af[mi], bf[ni], acc[mi][ni]);
  }
#pragma unroll
  for (int ni = 0; ni < 4; ni++) {
    int col = n0 + wn * 64 + ni * 16 + ln;
    float bhv = bh[col];
#pragma unroll
    for (int mi = 0; mi < 4; mi++) {
      int row = m0 + wm * 64 + mi * 16 + quad * 4;
#pragma unroll
      for (int r = 0; r < 4; r++)
        zg[(row + r) * DH + col] = f2bf(acc[mi][ni][r] + bhv);
    }
  }
}

// ---------------------------------------------------------------------------
// group barrier: 16 blocks of one row-group. Monotonic arrival counter.
// ---------------------------------------------------------------------------
__device__ inline void group_barrier(int* bar, int target) {
  __threadfence();                 // release this thread's stores (agent scope)
  __syncthreads();
  if (threadIdx.x == 0) {
    __hip_atomic_fetch_add(bar, 1, __ATOMIC_RELEASE, __HIP_MEMORY_SCOPE_AGENT);
    while (__hip_atomic_load(bar, __ATOMIC_ACQUIRE, __HIP_MEMORY_SCOPE_AGENT) < target)
      __builtin_amdgcn_s_sleep(2);
  }
  __syncthreads();
  __threadfence();                 // acquire: invalidate L1/L2 for fresh reads
}

// ---------------------------------------------------------------------------
// persistent RNN kernel. 256 blocks x 256 threads.
//   group g = bid>>4 owns batch rows [16g,16g+16); member = bid&15 owns cols
//   [64*member, 64*member+64); wave w owns 16 of those cols.
// ---------------------------------------------------------------------------
__global__ __launch_bounds__(256, 1) void rnn_kernel(
    const short* __restrict__ zg, const short* __restrict__ frag_w,
    short* __restrict__ h_buf, float* __restrict__ statsP,
    int* __restrict__ bars, const float* __restrict__ gamma,
    const float* __restrict__ beta, float* __restrict__ out) {
  const int tid = threadIdx.x, bid = blockIdx.x;
  const int g = bid >> 4, mem = bid & 15;
  const int w = tid >> 6, lane = tid & 63, ln = lane & 15, quad = lane >> 4;
  const int colw = mem * 64 + w * 16 + ln;     // this lane's output column
  const int rowBase = g * 16;                  // group's batch-row base

  __shared__ short Alds[16 * 1032];            // 16 x 1024 bf16, +8 pad (33KB)
  __shared__ float sSum[4][16], sSq[4][16];
  __shared__ float meanL[16], rstdL[16];

  // W_h B-operand fragments: resident in VGPRs for the whole kernel (128 VGPR)
  s16x8 Wf[32];
  {
    const s16x8* fw = (const s16x8*)frag_w + (size_t)(mem * 4 + w) * 32 * 64;
#pragma unroll
    for (int ks = 0; ks < 32; ks++) Wf[ks] = fw[ks * 64 + lane];
  }
  const float gam = gamma[colw], bet = beta[colw];
  int* gbar = &bars[g * 32];
  int barTarget = 0;

#pragma unroll 1
  for (int t = 0; t < T_STEPS; t++) {
    // ---- Phase A: stage h -> LDS (row = tid&15: 2-way bank aliasing, free)
    {
      int r = tid & 15, seg = (tid >> 4) * 64;
      const s16x8* src = (const s16x8*)(h_buf + (rowBase + r) * DH + seg);
      s16x8* dst = (s16x8*)&Alds[r * 1032 + seg];
#pragma unroll
      for (int i = 0; i < 8; i++) dst[i] = src[i];
    }
    __syncthreads();

    // ---- GEMM: pre-tile (16 rows x 16 cols per wave), K=1024
    f32x4 acc0 = {0.f, 0.f, 0.f, 0.f}, acc1 = {0.f, 0.f, 0.f, 0.f};
#pragma unroll
    for (int ks = 0; ks < 32; ks += 2) {
      s16x8 a0 = *(const s16x8*)&Alds[ln * 1032 + ks * 32 + quad * 8];
      s16x8 a1 = *(const s16x8*)&Alds[ln * 1032 + ks * 32 + 32 + quad * 8];
      acc0 = mfma16x32(a0, Wf[ks], acc0);
      acc1 = mfma16x32(a1, Wf[ks + 1], acc1);
    }
    // add zg (+b_h already folded in)
    float pre[4];
    {
      int zbase = (t * B_SZ + rowBase + quad * 4) * DH + colw;
#pragma unroll
      for (int r = 0; r < 4; r++)
        pre[r] = acc0[r] + acc1[r] + bf2f(zg[zbase + r * DH]);
    }
    // per-row partial LN stats over this wave's 16 columns
#pragma unroll
    for (int r = 0; r < 4; r++) {
      float s = rsum16(pre[r]);
      float q = rsum16(pre[r] * pre[r]);
      if (ln == 0) { sSum[w][quad * 4 + r] = s; sSq[w][quad * 4 + r] = q; }
    }
    __syncthreads();
    if (tid < 16) {
      float s = sSum[0][tid] + sSum[1][tid] + sSum[2][tid] + sSum[3][tid];
      float q = sSq[0][tid] + sSq[1][tid] + sSq[2][tid] + sSq[3][tid];
      int o = ((g * 16 + mem) * 16 + tid) * 2;
      statsP[o] = s; statsP[o + 1] = q;
    }
    barTarget += 16;
    group_barrier(gbar, barTarget);

    // ---- Phase B: full-row stats, normalize, relu, store
    if (tid < 16) {
      float s = 0.f, q = 0.f;
      for (int m2 = 0; m2 < 16; m2++) {
        int o = ((g * 16 + m2) * 16 + tid) * 2;
        s += statsP[o]; q += statsP[o + 1];
      }
      float mean = s * (1.0f / 1024.0f);
      float var = q * (1.0f / 1024.0f) - mean * mean;
      meanL[tid] = mean;
      rstdL[tid] = rsqrtf(var + 1e-5f);
    }
    __syncthreads();
#pragma unroll
    for (int r = 0; r < 4; r++) {
      int row = quad * 4 + r;
      float hv = (pre[r] - meanL[row]) * rstdL[row] * gam + bet;
      hv = fmaxf(hv, 0.0f);
      out[(t * B_SZ + rowBase + row) * DH + colw] = hv;
      h_buf[(rowBase + row) * DH + colw] = f2bf(hv);
    }
    barTarget += 16;
    group_barrier(gbar, barTarget);
  }
}

// ---------------------------------------------------------------------------
extern "C" void kernel_launch(void* const* d_in, const int* in_sizes, int n_in,
                              void* d_out, int out_size, void* d_ws, size_t ws_size,
                              hipStream_t stream) {
  const float* Z   = (const float*)d_in[0];   // [128,256,512]
  const float* Wh  = (const float*)d_in[1];   // [1024,1024]
  const float* Wg  = (const float*)d_in[2];   // [1024,512]
  const float* bh  = (const float*)d_in[3];   // [1024]
  const float* gam = (const float*)d_in[4];   // [1024]
  const float* bet = (const float*)d_in[5];   // [1024]
  float* out = (float*)d_out;                 // [128,256,1024] fp32

  // workspace layout (~66.5 MiB total)
  char* ws = (char*)d_ws;
  short*    zg     = (short*)(ws);                 // 32768*1024 bf16 = 67,108,864 B
  short*    frag_w = (short*)(ws + 67108864);      // 1,048,576 bf16  =  2,097,152 B
  short*    h_buf  = (short*)(ws + 69206016);      // 256*1024 bf16   =    524,288 B
  float*    statsP = (float*)(ws + 69730304);      // 16*16*16*2 f32  =     32,768 B
  int*      bars   = (int*)  (ws + 69763072);      // 512 ints        =      2,048 B

  prep_kernel<<<4096, 256, 0, stream>>>(Wh, frag_w, (unsigned*)h_buf, bars);
  zg_gemm<<<dim3(256, 8), 256, 0, stream>>>(Z, Wg, bh, zg);
  rnn_kernel<<<256, 256, 0, stream>>>(zg, frag_w, h_buf, statsP, bars, gam, bet, out);
}

// Round 2
// 888.038 us; speedup vs baseline: 14.4466x; 14.4466x over previous
//
#include <hip/hip_runtime.h>

// Problem: T=128, B=256, D_G=512, D_H=1024
//   zg = z @ W_g^T + b_h   (one big GEMM, precomputed)
//   h_t = relu(LN(h_{t-1} @ W_h^T + zg_t)), h_0 = 0; out = all h_t (fp32)
//
// Persistent RNN kernel: 256 blocks x 256 threads (1 block/CU).
//   16 row-groups (16 batch rows) x 16 column-members (64 cols each).
//   W_h slice pinned in 128 VGPRs. ONE group barrier per step; all
//   cross-block traffic via relaxed agent-scope atomics (sc0/sc1 cache
//   bypass, coherent at memory-side L3) -- NO fences, NO L2 flushes.
// Per step: GEMM(h_{t-1} in LDS) -> publish pre+stats -> barrier ->
//   gather stats + normalize while staging h_t into LDS + write out[t].

#define T_STEPS 128
#define B_SZ    256
#define DG      512
#define DH      1024

typedef short s16x8 __attribute__((ext_vector_type(8)));   // 8 bf16
typedef short s16x4 __attribute__((ext_vector_type(4)));
typedef float f32x4 __attribute__((ext_vector_type(4)));
typedef unsigned long long u64;

__device__ inline short f2bf(float f) {
  unsigned u = __builtin_bit_cast(unsigned, f);
  unsigned r = (u + 0x7fffu + ((u >> 16) & 1u)) >> 16;   // RNE
  return (short)r;
}
__device__ inline float bf2f(short h) {
  unsigned u = ((unsigned)(unsigned short)h) << 16;
  return __builtin_bit_cast(float, u);
}
__device__ inline s16x8 pk8(f32x4 a, f32x4 b) {
  s16x8 r;
  r[0] = f2bf(a[0]); r[1] = f2bf(a[1]); r[2] = f2bf(a[2]); r[3] = f2bf(a[3]);
  r[4] = f2bf(b[0]); r[5] = f2bf(b[1]); r[6] = f2bf(b[2]); r[7] = f2bf(b[3]);
  return r;
}
__device__ inline f32x4 mfma16x32(s16x8 a, s16x8 b, f32x4 c) {
  return __builtin_amdgcn_mfma_f32_16x16x32_bf16(a, b, c, 0, 0, 0);
}
__device__ inline float rsum16(float v) {
  v += __shfl_xor(v, 1);
  v += __shfl_xor(v, 2);
  v += __shfl_xor(v, 4);
  v += __shfl_xor(v, 8);
  return v;
}
#define ATOM_ST(p, v) __hip_atomic_store((p), (v), __ATOMIC_RELAXED, __HIP_MEMORY_SCOPE_AGENT)
#define ATOM_LD(p)    __hip_atomic_load((p), __ATOMIC_RELAXED, __HIP_MEMORY_SCOPE_AGENT)

// ---------------------------------------------------------------------------
// prep: W_h fragments in MFMA B-operand lane layout (bf16); zero barriers.
// frag layout: [memblk 16][wave 4][kstep 32][lane 64][j 8]
//   value = W_h[memblk*64 + wave*16 + (lane&15)][kstep*32 + (lane>>4)*8 + j]
// ---------------------------------------------------------------------------
__global__ __launch_bounds__(256) void prep_kernel(
    const float* __restrict__ Wh, short* __restrict__ frag_w,
    int* __restrict__ bars) {
  int i = blockIdx.x * 256 + threadIdx.x;              // grid 4096 -> 1,048,576
  int j    = i & 7;
  int lane = (i >> 3) & 63;
  int ks   = (i >> 9) & 31;
  int w    = (i >> 14) & 3;
  int b    = i >> 16;
  int row = b * 64 + w * 16 + (lane & 15);
  int col = ks * 32 + (lane >> 4) * 8 + j;
  frag_w[i] = f2bf(Wh[row * DH + col]);
  if (i < 512) bars[i] = 0;
}

// ---------------------------------------------------------------------------
// zg GEMM: zg[t*B+b][n] = sum_k z[t*B+b][k]*W_g[n][k] + b_h[n]  (bf16 out)
// ---------------------------------------------------------------------------
__global__ __launch_bounds__(256) void zg_gemm(
    const float* __restrict__ Z, const float* __restrict__ Wg,
    const float* __restrict__ bh, short* __restrict__ zg) {
  const int tid  = threadIdx.x;
  const int m0   = blockIdx.x * 128;
  const int n0   = blockIdx.y * 128;
  const int w    = tid >> 6, lane = tid & 63, ln = lane & 15, quad = lane >> 4;
  const int wm   = w & 1, wn = w >> 1;
  const int srow = tid >> 1, shalf = tid & 1;

  __shared__ short As[128 * 40];
  __shared__ short Bs[128 * 40];
  f32x4 acc[4][4] = {};

  for (int k0 = 0; k0 < DG; k0 += 32) {
    __syncthreads();
    {
      const float* sA = Z + (m0 + srow) * DG + k0 + shalf * 16;
      f32x4 a0 = *(const f32x4*)sA,       a1 = *(const f32x4*)(sA + 4);
      f32x4 a2 = *(const f32x4*)(sA + 8), a3 = *(const f32x4*)(sA + 12);
      s16x8* dA = (s16x8*)&As[srow * 40 + shalf * 16];
      dA[0] = pk8(a0, a1); dA[1] = pk8(a2, a3);
      const float* sB = Wg + (n0 + srow) * DG + k0 + shalf * 16;
      f32x4 b0 = *(const f32x4*)sB,       b1 = *(const f32x4*)(sB + 4);
      f32x4 b2 = *(const f32x4*)(sB + 8), b3 = *(const f32x4*)(sB + 12);
      s16x8* dB = (s16x8*)&Bs[srow * 40 + shalf * 16];
      dB[0] = pk8(b0, b1); dB[1] = pk8(b2, b3);
    }
    __syncthreads();
    s16x8 af[4], bf[4];
#pragma unroll
    for (int i = 0; i < 4; i++) {
      af[i] = *(const s16x8*)&As[(wm * 64 + i * 16 + ln) * 40 + quad * 8];
      bf[i] = *(const s16x8*)&Bs[(wn * 64 + i * 16 + ln) * 40 + quad * 8];
    }
#pragma unroll
    for (int mi = 0; mi < 4; mi++)
#pragma unroll
      for (int ni = 0; ni < 4; ni++)
        acc[mi][ni] = mfma16x32(af[mi], bf[ni], acc[mi][ni]);
  }
#pragma unroll
  for (int ni = 0; ni < 4; ni++) {
    int col = n0 + wn * 64 + ni * 16 + ln;
    float bhv = bh[col];
#pragma unroll
    for (int mi = 0; mi < 4; mi++) {
      int row = m0 + wm * 64 + mi * 16 + quad * 4;
#pragma unroll
      for (int r = 0; r < 4; r++)
        zg[(row + r) * DH + col] = f2bf(acc[mi][ni][r] + bhv);
    }
  }
}

// ---------------------------------------------------------------------------
// persistent RNN. group g = bid>>4 owns rows [16g,16g+16); member = bid&15
// owns cols [64m,64m+64); wave w owns 16 cols of those.
// ---------------------------------------------------------------------------
__global__ __launch_bounds__(256, 1) void rnn_kernel(
    const short* __restrict__ zg, const short* __restrict__ frag_w,
    short* __restrict__ pre_buf,            // [2][256][1024] bf16
    u64* __restrict__ stats,                // [2][16][16 mem][16 row]
    int* __restrict__ bars, const float* __restrict__ gamma,
    const float* __restrict__ beta, float* __restrict__ out) {
  const int tid = threadIdx.x, bid = blockIdx.x;
  const int g = bid >> 4, mem = bid & 15;
  const int w = tid >> 6, lane = tid & 63, ln = lane & 15, quad = lane >> 4;
  const int colw = mem * 64 + w * 16 + ln;     // GEMM output column
  const int rowBase = g * 16;
  const int sr = tid >> 4, sj = tid & 15;      // stage role: row, col-team

  __shared__ short Alds[16 * 1032];            // h state, 16 x 1024 (+8 pad)
  __shared__ float sSum[4][16], sSq[4][16];    // per-wave LN partials
  __shared__ float sS[16][16], sQ[16][16];     // gathered member stats
  __shared__ float gbe[2][1024];               // gamma, beta

  // init LDS: gamma/beta, zero h state
  for (int i = tid; i < 1024; i += 256) { gbe[0][i] = gamma[i]; gbe[1][i] = beta[i]; }
  {
    s16x8 z8 = {};
    for (int c = tid; c < 2064; c += 256) ((s16x8*)Alds)[c] = z8;
  }
  // W_h B-fragments resident in VGPRs (128 VGPR)
  s16x8 Wf[32];
  {
    const s16x8* fw = (const s16x8*)frag_w + (size_t)(mem * 4 + w) * 32 * 64;
#pragma unroll
    for (int ks = 0; ks < 32; ks++) Wf[ks] = fw[ks * 64 + lane];
  }
  int* gbar = &bars[g * 32];
  __syncthreads();

#pragma unroll 1
  for (int t = 0; t < T_STEPS; t++) {
    const int p = t & 1;
    // pin Wf in VGPRs (prevents per-iteration rematerialization from memory)
#pragma unroll
    for (int i2 = 0; i2 < 32; i2++) asm volatile("" : "+v"(Wf[i2]));

    // ---- GEMM on h_{t-1} (in LDS): 16 rows x 16 cols per wave, K=1024
    f32x4 acc0 = {0.f, 0.f, 0.f, 0.f}, acc1 = {0.f, 0.f, 0.f, 0.f};
#pragma unroll
    for (int ks = 0; ks < 32; ks += 2) {
      s16x8 a0 = *(const s16x8*)&Alds[ln * 1032 + ks * 32 + quad * 8];
      s16x8 a1 = *(const s16x8*)&Alds[ln * 1032 + ks * 32 + 32 + quad * 8];
      acc0 = mfma16x32(a0, Wf[ks], acc0);
      acc1 = mfma16x32(a1, Wf[ks + 1], acc1);
    }
    // pre = acc + zg[t]; publish bf16 pre + per-wave LN partials
    float pre[4];
    {
      int zbase = (t * B_SZ + rowBase + quad * 4) * DH + colw;
#pragma unroll
      for (int r = 0; r < 4; r++)
        pre[r] = acc0[r] + acc1[r] + bf2f(zg[zbase + r * DH]);
    }
#pragma unroll
    for (int r = 0; r < 4; r++) {
      int grow = p * B_SZ + rowBase + quad * 4 + r;
      ATOM_ST(&pre_buf[grow * DH + colw], f2bf(pre[r]));
      float s = rsum16(pre[r]);
      float q = rsum16(pre[r] * pre[r]);
      if (ln == 0) { sSum[w][quad * 4 + r] = s; sSq[w][quad * 4 + r] = q; }
    }
    __syncthreads();
    if (tid < 16) {
      float s = sSum[0][tid] + sSum[1][tid] + sSum[2][tid] + sSum[3][tid];
      float q = sSq[0][tid] + sSq[1][tid] + sSq[2][tid] + sSq[3][tid];
      float2 f2; f2.x = s; f2.y = q;
      ATOM_ST(&stats[((p * 16 + g) * 16 + mem) * 16 + tid],
              __builtin_bit_cast(u64, f2));
    }
    // ---- ONE group barrier (arrive after all publishes drained)
    __syncthreads();                       // drains vmcnt -> stores visible
    if (tid == 0) {
      __hip_atomic_fetch_add(gbar, 1, __ATOMIC_RELAXED, __HIP_MEMORY_SCOPE_AGENT);
      int target = (t + 1) * 16;
      while (__hip_atomic_load(gbar, __ATOMIC_RELAXED, __HIP_MEMORY_SCOPE_AGENT) < target)
        __builtin_amdgcn_s_sleep(1);
    }
    __syncthreads();

    // ---- stage: gather all-cols pre_t + stats; normalize; h_t -> LDS; out
    u64 pr[16];
    {
      const u64* preU = (const u64*)pre_buf;
      int rbase = (p * B_SZ + rowBase + sr) * (DH / 4);
#pragma unroll
      for (int k = 0; k < 16; k++)
        pr[k] = ATOM_LD(&preU[rbase + k * 16 + sj]);
    }
    {
      int m2 = tid >> 4, row = tid & 15;
      float2 f2 = __builtin_bit_cast(float2,
          ATOM_LD(&stats[((p * 16 + g) * 16 + m2) * 16 + row]));
      sS[m2][row] = f2.x; sQ[m2][row] = f2.y;
    }
    __syncthreads();
    float mean, rstd;
    {
      float s = 0.f, q = 0.f;
#pragma unroll
      for (int m2 = 0; m2 < 16; m2++) { s += sS[m2][sr]; q += sQ[m2][sr]; }
      mean = s * (1.0f / 1024.0f);
      float var = q * (1.0f / 1024.0f) - mean * mean;
      rstd = __frsqrt_rn(var + 1e-5f);
    }
    {
      float* orow = out + (size_t)(t * B_SZ + rowBase + sr) * DH;
      short* lrow = &Alds[sr * 1032];
#pragma unroll
      for (int k = 0; k < 16; k++) {
        int c = k * 64 + sj * 4;
        s16x4 pv = __builtin_bit_cast(s16x4, pr[k]);
        f32x4 hv; s16x4 hb;
#pragma unroll
        for (int i = 0; i < 4; i++) {
          float x = (bf2f(pv[i]) - mean) * rstd * gbe[0][c + i] + gbe[1][c + i];
          x = fmaxf(x, 0.0f);
          hv[i] = x; hb[i] = f2bf(x);
        }
        *(f32x4*)&orow[c] = hv;
        *(s16x4*)&lrow[c] = hb;
      }
    }
    __syncthreads();                       // h_t in LDS ready for next GEMM
  }
}

// ---------------------------------------------------------------------------
extern "C" void kernel_launch(void* const* d_in, const int* in_sizes, int n_in,
                              void* d_out, int out_size, void* d_ws, size_t ws_size,
                              hipStream_t stream) {
  const float* Z   = (const float*)d_in[0];   // [128,256,512]
  const float* Wh  = (const float*)d_in[1];   // [1024,1024]
  const float* Wg  = (const float*)d_in[2];   // [1024,512]
  const float* bh  = (const float*)d_in[3];   // [1024]
  const float* gam = (const float*)d_in[4];   // [1024]
  const float* bet = (const float*)d_in[5];   // [1024]
  float* out = (float*)d_out;                 // [128,256,1024] fp32

  char* ws = (char*)d_ws;
  short* zg      = (short*)(ws);               // 64 MiB
  short* frag_w  = (short*)(ws + 67108864);    // 2 MiB
  short* pre_buf = (short*)(ws + 69206016);    // [2][256][1024] bf16 = 1 MiB
  u64*   stats   = (u64*)  (ws + 70254592);    // [2][16][16][16] u64 = 64 KiB
  int*   bars    = (int*)  (ws + 70320128);    // 512 ints

  prep_kernel<<<4096, 256, 0, stream>>>(Wh, frag_w, bars);
  zg_gemm<<<dim3(256, 8), 256, 0, stream>>>(Z, Wg, bh, zg);
  rnn_kernel<<<256, 256, 0, stream>>>(zg, frag_w, pre_buf, stats, bars, gam, bet, out);
}